// Round 1
// baseline (458.905 us; speedup 1.0000x reference)
//
#include <hip/hip_runtime.h>
#include <hip/hip_bf16.h>
#include <cstdint>

#define DEVINL __device__ __forceinline__

typedef __attribute__((ext_vector_type(8))) short short8;   // 8 x bf16 (guide §3)
typedef __attribute__((ext_vector_type(4))) float f32x4;

constexpr int B_ = 2, S_ = 2048, H_ = 1024, NH_ = 16, HD_ = 64;
constexpr int M_ = B_ * S_;          // 4096 token rows
constexpr float SCALE = 0.125f;      // 1/sqrt(64)

DEVINL float bf2f(unsigned short h) {
    unsigned u = ((unsigned)h) << 16;
    float f; __builtin_memcpy(&f, &u, 4); return f;
}
DEVINL unsigned short f2bf(float f) {  // RNE truncate
    unsigned u; __builtin_memcpy(&u, &f, 4);
    u += 0x7FFFu + ((u >> 16) & 1u);
    return (unsigned short)(u >> 16);
}
DEVINL float ldin(const void* p, size_t i, int fp32) {
    return fp32 ? ((const float*)p)[i] : bf2f(((const unsigned short*)p)[i]);
}
DEVINL void gl16(const void* g, void* l) {  // async global->LDS, 16B/lane
    __builtin_amdgcn_global_load_lds(
        (const __attribute__((address_space(1))) unsigned int*)g,
        (__attribute__((address_space(3))) unsigned int*)l, 16, 0, 0);
}
DEVINL f32x4 mfma16(short8 a, short8 b, f32x4 c) {
    return __builtin_amdgcn_mfma_f32_16x16x32_bf16(a, b, c, 0, 0, 0);
}

// ---------------------------------------------------------------------------
// Mode detect: are float inputs fp32 or bf16? Sample even halfwords of emb.
// bf16 mode: halfword 2t IS a bf16 value of N(0,0.02) -> exponent in [90,126].
// fp32 mode: halfword 2t is a mantissa half -> ~uniform exponent (~15% hit).
// flag = 1 -> fp32 inputs/outputs; flag = 0 -> bf16.
// ---------------------------------------------------------------------------
__global__ __launch_bounds__(256) void k_detect(const unsigned short* __restrict__ emb,
                                                int* __restrict__ flag) {
    int t = threadIdx.x;
    unsigned short hw = emb[2 * t];
    unsigned e = (hw >> 7) & 0xFFu;
    int plaus = ((e >= 90u) && (e <= 126u)) || ((hw & 0x7FFFu) == 0u);
    __shared__ int cnt[4];
    int s = plaus;
    #pragma unroll
    for (int o = 1; o < 64; o <<= 1) s += __shfl_xor(s, o);
    if ((t & 63) == 0) cnt[t >> 6] = s;
    __syncthreads();
    if (t == 0) flag[0] = ((cnt[0] + cnt[1] + cnt[2] + cnt[3]) > 192) ? 0 : 1;
}

__global__ __launch_bounds__(256) void k_bias(const void* bq, const void* bk,
                                              const void* bv, const void* bo,
                                              const int* __restrict__ flag,
                                              float* __restrict__ out) {
    int i = blockIdx.x * 256 + threadIdx.x;  // 0..4095
    int fp32 = flag[0];
    const void* src = (i < 1024) ? bq : (i < 2048) ? bk : (i < 3072) ? bv : bo;
    out[i] = ldin(src, (size_t)(i & 1023), fp32);
}

// Transpose+convert 1024x1024 weight -> wT[n][k] (bf16) so GEMM B-frags load
// like A-frags (verified B^T structure).
__global__ __launch_bounds__(256) void k_transw(const void* w0, const void* w1,
                                                const void* w2, const void* w3,
                                                const int* __restrict__ flag,
                                                unsigned short* __restrict__ wT) {
    __shared__ float tile[32][33];
    int mat = blockIdx.z;
    const void* w = (mat == 0) ? w0 : (mat == 1) ? w1 : (mat == 2) ? w2 : w3;
    int fp32 = flag[0];
    int n0 = blockIdx.x * 32, k0 = blockIdx.y * 32;
    int tx = threadIdx.x, ty = threadIdx.y;
    for (int i = ty; i < 32; i += 8)
        tile[i][tx] = ldin(w, (size_t)(k0 + i) * 1024 + n0 + tx, fp32);
    __syncthreads();
    unsigned short* dst = wT + (size_t)mat * 1024 * 1024;
    for (int i = ty; i < 32; i += 8)
        dst[(size_t)(n0 + i) * 1024 + k0 + tx] = f2bf(tile[tx][i]);
}

// Embedding gather -> bf16 h (4096 x 1024). One block per token row.
__global__ __launch_bounds__(256) void k_gather(const int* __restrict__ batch,
                                                const void* __restrict__ emb,
                                                const int* __restrict__ flag,
                                                unsigned short* __restrict__ h) {
    int row = blockIdx.x, t = threadIdx.x;
    int tok = batch[row];
    unsigned short* dst = h + (size_t)row * H_;
    if (flag[0]) {
        const float4* s = (const float4*)((const float*)emb + (size_t)tok * H_);
        float4 x = s[t];
        unsigned long long pk = (unsigned long long)f2bf(x.x)
                              | ((unsigned long long)f2bf(x.y) << 16)
                              | ((unsigned long long)f2bf(x.z) << 32)
                              | ((unsigned long long)f2bf(x.w) << 48);
        ((unsigned long long*)dst)[t] = pk;
    } else {
        ((uint2*)dst)[t] =
            ((const uint2*)((const unsigned short*)emb + (size_t)tok * H_))[t];
    }
}

// ---------------------------------------------------------------------------
// 128x128 bf16 MFMA GEMM, A: MxK row-major, Bt: NxK row-major (pre-transposed),
// C = A*Bt^T + bias.  m97-style: global_load_lds(16B) staging, 2 barriers/K-step.
// Cf != null => final output: write fp32 if mode flag says fp32, else bf16.
// ---------------------------------------------------------------------------
__global__ __launch_bounds__(256) void k_gemm(const unsigned short* __restrict__ A,
                                              const unsigned short* __restrict__ Bt,
                                              const float* __restrict__ bias,
                                              unsigned short* __restrict__ Cb,
                                              float* __restrict__ Cf,
                                              const int* __restrict__ flag,
                                              int M, int N, int K) {
    __shared__ alignas(16) unsigned short As[128 * 32];
    __shared__ alignas(16) unsigned short Bs[128 * 32];
    int t = threadIdx.x, lane = t & 63, quad = lane >> 4, n16 = lane & 15;
    int w = t >> 6, wm = w >> 1, wn = w & 1;
    int m0 = blockIdx.y * 128, n0 = blockIdx.x * 128;
    f32x4 acc[4][4];
    #pragma unroll
    for (int mi = 0; mi < 4; mi++)
        #pragma unroll
        for (int ni = 0; ni < 4; ni++) acc[mi][ni] = (f32x4){0.f, 0.f, 0.f, 0.f};
    int c0 = t, c1 = t + 256;
    int ra0 = c0 >> 2, ka0 = (c0 & 3) * 8;
    int ra1 = c1 >> 2, ka1 = (c1 & 3) * 8;
    for (int k0 = 0; k0 < K; k0 += 32) {
        __syncthreads();
        gl16(A  + (size_t)(m0 + ra0) * K + k0 + ka0, &As[c0 * 8]);
        gl16(A  + (size_t)(m0 + ra1) * K + k0 + ka1, &As[c1 * 8]);
        gl16(Bt + (size_t)(n0 + ra0) * K + k0 + ka0, &Bs[c0 * 8]);
        gl16(Bt + (size_t)(n0 + ra1) * K + k0 + ka1, &Bs[c1 * 8]);
        __syncthreads();
        short8 af[4], bfr[4];
        #pragma unroll
        for (int mi = 0; mi < 4; mi++)
            af[mi] = *(const short8*)&As[(wm * 64 + mi * 16 + n16) * 32 + quad * 8];
        #pragma unroll
        for (int ni = 0; ni < 4; ni++)
            bfr[ni] = *(const short8*)&Bs[(wn * 64 + ni * 16 + n16) * 32 + quad * 8];
        #pragma unroll
        for (int mi = 0; mi < 4; mi++)
            #pragma unroll
            for (int ni = 0; ni < 4; ni++)
                acc[mi][ni] = mfma16(af[mi], bfr[ni], acc[mi][ni]);
    }
    int fp32out = (Cf != nullptr) && (flag[0] == 1);
    #pragma unroll
    for (int mi = 0; mi < 4; mi++) {
        #pragma unroll
        for (int ni = 0; ni < 4; ni++) {
            int row = m0 + wm * 64 + mi * 16 + quad * 4;   // C row = quad*4+reg (m89)
            int col = n0 + wn * 64 + ni * 16 + n16;        // C col = lane&15
            float bb = bias[col];
            #pragma unroll
            for (int i = 0; i < 4; i++) {
                float val = acc[mi][ni][i] + bb;
                size_t idx = (size_t)(row + i) * N + col;
                if (fp32out) Cf[idx] = val;
                else         Cb[idx] = f2bf(val);
            }
        }
    }
}

// In-place RoPE on q and k (bf16). One thread per (tensor,row,head,d<32) pair.
__global__ __launch_bounds__(256) void k_rope(unsigned short* __restrict__ q,
                                              unsigned short* __restrict__ k_,
                                              const int* __restrict__ positions) {
    unsigned idx = blockIdx.x * 256u + threadIdx.x;  // < 2^22
    unsigned ts = idx >> 21;
    unsigned row = (idx >> 9) & 4095u;
    unsigned p = idx & 511u;
    unsigned head = p >> 5, d = p & 31u;
    unsigned short* buf = ts ? k_ : q;
    size_t base = (size_t)row * H_ + head * HD_ + d;
    float x1 = bf2f(buf[base]);
    float x2 = bf2f(buf[base + 32]);
    float pos = (float)positions[row];
    float invf = 1.0f / powf(10000.0f, (float)d * (1.0f / 32.0f));
    float ang = pos * invf;
    float cs = cosf(ang), sn = sinf(ang);
    buf[base]      = f2bf(x1 * cs - x2 * sn);
    buf[base + 32] = f2bf(x2 * cs + x1 * sn);
}

// ---------------------------------------------------------------------------
// Flash attention. Block = 4 waves x 16 query rows = 64 queries of one (b,h).
// 32-key tiles: K staged row-major (global_load_lds), V staged transposed with
// XOR swizzle (b128-friendly PV B-frags). Online softmax per C-layout row.
// ---------------------------------------------------------------------------
__global__ __launch_bounds__(256) void k_attn(const unsigned short* __restrict__ q,
                                              const unsigned short* __restrict__ k_,
                                              const unsigned short* __restrict__ v,
                                              const int* __restrict__ lengths,
                                              unsigned short* __restrict__ o) {
    __shared__ alignas(16) unsigned short Ks[32 * 64];     // [key][feat]
    __shared__ alignas(16) unsigned short Vs[64 * 32];     // [feat][key] swizzled
    __shared__ alignas(16) unsigned short Ps[4][16 * 40];  // per-wave P, pad 40
    int bx = blockIdx.x;
    int qt = bx & 31, hh = (bx >> 5) & 15, b = bx >> 9;
    int t = threadIdx.x, w = t >> 6, lane = t & 63, quad = lane >> 4, n16 = lane & 15;
    int len = lengths[b];
    int kend = min(qt * 64 + 64, len);        // union of allowed keys for block
    int nkb = (kend + 31) >> 5;               // >=1 since len>=1
    size_t qbase = ((size_t)(b * S_ + qt * 64 + w * 16 + n16)) * H_ + hh * HD_ + quad * 8;
    short8 aq0 = *(const short8*)(q + qbase);          // A-frag k 0..31
    short8 aq1 = *(const short8*)(q + qbase + 32);     // A-frag k 32..63
    f32x4 oacc[4];
    float mrow[4], lrow[4];
    #pragma unroll
    for (int i = 0; i < 4; i++) {
        oacc[i] = (f32x4){0.f, 0.f, 0.f, 0.f};
        mrow[i] = -__builtin_inff(); lrow[i] = 0.f;
    }
    int qrow0 = qt * 64 + w * 16 + quad * 4;
    int r = t >> 3, c = t & 7;                              // staging: key row, 8-feat chunk
    int kpos = ((((r >> 3) ^ (c & 3)) << 3) | (r & 7));     // swizzled key slot
    for (int kb = 0; kb < nkb; kb++) {
        __syncthreads();  // prev PV done before restage
        size_t krow = ((size_t)(b * S_ + kb * 32 + r)) * H_ + hh * HD_ + c * 8;
        gl16(k_ + krow, &Ks[t * 8]);
        short8 vv = *(const short8*)(v + krow);
        #pragma unroll
        for (int j = 0; j < 8; j++)
            Vs[(c * 8 + j) * 32 + kpos] = (unsigned short)vv[j];
        __syncthreads();  // staging visible (drains vmcnt incl. global_load_lds)
        f32x4 sc[2];
        #pragma unroll
        for (int half = 0; half < 2; half++) {
            const unsigned short* kr = &Ks[(half * 16 + n16) * 64 + quad * 8];
            short8 b0 = *(const short8*)kr;
            short8 b1 = *(const short8*)(kr + 32);
            f32x4 z = (f32x4){0.f, 0.f, 0.f, 0.f};
            z = mfma16(aq0, b0, z);
            z = mfma16(aq1, b1, z);
            sc[half] = z;
        }
        int kbase = kb * 32;
        float al[4];
        #pragma unroll
        for (int i = 0; i < 4; i++) {
            int qr = qrow0 + i;
            #pragma unroll
            for (int half = 0; half < 2; half++) {
                int kg = kbase + half * 16 + n16;
                float sv = sc[half][i] * SCALE;
                sc[half][i] = ((kg <= qr) && (kg < len)) ? sv : -__builtin_inff();
            }
            float tm = fmaxf(sc[0][i], sc[1][i]);
            tm = fmaxf(tm, __shfl_xor(tm, 1));
            tm = fmaxf(tm, __shfl_xor(tm, 2));
            tm = fmaxf(tm, __shfl_xor(tm, 4));
            tm = fmaxf(tm, __shfl_xor(tm, 8));
            float mnew = fmaxf(mrow[i], tm);   // finite from block 0 (key 0 always valid)
            al[i] = __expf(mrow[i] - mnew);
            float p0 = __expf(sc[0][i] - mnew);
            float p1 = __expf(sc[1][i] - mnew);
            float rs = p0 + p1;
            rs += __shfl_xor(rs, 1); rs += __shfl_xor(rs, 2);
            rs += __shfl_xor(rs, 4); rs += __shfl_xor(rs, 8);
            lrow[i] = al[i] * lrow[i] + rs;
            mrow[i] = mnew;
            Ps[w][(quad * 4 + i) * 40 + n16]      = f2bf(p0);
            Ps[w][(quad * 4 + i) * 40 + 16 + n16] = f2bf(p1);
        }
        f32x4 alv = (f32x4){al[0], al[1], al[2], al[3]};
        #pragma unroll
        for (int nb = 0; nb < 4; nb++) oacc[nb] *= alv;
        __syncthreads();  // Ps (cross-lane) visible
        short8 ap = *(const short8*)&Ps[w][n16 * 40 + quad * 8];  // P in A-layout
        #pragma unroll
        for (int nb = 0; nb < 4; nb++) {
            int f = nb * 16 + n16;
            int grp = quad ^ ((f >> 3) & 3);
            short8 bv = *(const short8*)&Vs[f * 32 + grp * 8];
            oacc[nb] = mfma16(ap, bv, oacc[nb]);
        }
    }
    f32x4 rcp = (f32x4){1.f / lrow[0], 1.f / lrow[1], 1.f / lrow[2], 1.f / lrow[3]};
    #pragma unroll
    for (int nb = 0; nb < 4; nb++) {
        f32x4 ov = oacc[nb] * rcp;
        #pragma unroll
        for (int i = 0; i < 4; i++) {
            size_t idx = ((size_t)(b * S_ + qrow0 + i)) * H_ + hh * HD_ + nb * 16 + n16;
            o[idx] = f2bf(ov[i]);
        }
    }
}

extern "C" void kernel_launch(void* const* d_in, const int* in_sizes, int n_in,
                              void* d_out, int out_size, void* d_ws, size_t ws_size,
                              hipStream_t stream) {
    (void)in_sizes; (void)n_in; (void)out_size; (void)ws_size;
    const int* batch     = (const int*)d_in[0];
    const int* positions = (const int*)d_in[1];
    const int* lengths   = (const int*)d_in[2];
    const void* emb = d_in[3];
    const void* wq = d_in[4];  const void* bq = d_in[5];
    const void* wk = d_in[6];  const void* bk = d_in[7];
    const void* wv = d_in[8];  const void* bv = d_in[9];
    const void* wo = d_in[10]; const void* bo = d_in[11];

    char* ws = (char*)d_ws;
    int*   flag   = (int*)ws;                                   // 4 KB slot
    float* biasws = (float*)(ws + 4096);                        // 16 KB [bq|bk|bv|bo]
    unsigned short* wT = (unsigned short*)(ws + 20480);         // 4 x 1M bf16
    size_t off = 20480 + (8ull << 20);
    unsigned short* hbuf = (unsigned short*)(ws + off); off += (8ull << 20);
    unsigned short* qb   = (unsigned short*)(ws + off); off += (8ull << 20);
    unsigned short* kb2  = (unsigned short*)(ws + off); off += (8ull << 20);
    unsigned short* vb   = (unsigned short*)(ws + off); off += (8ull << 20);
    unsigned short* ao   = (unsigned short*)(ws + off); off += (8ull << 20);

    k_detect<<<1, 256, 0, stream>>>((const unsigned short*)emb, flag);
    k_bias<<<16, 256, 0, stream>>>(bq, bk, bv, bo, flag, biasws);
    k_transw<<<dim3(32, 32, 4), dim3(32, 8), 0, stream>>>(wq, wk, wv, wo, flag, wT);
    k_gather<<<M_, 256, 0, stream>>>(batch, emb, flag, hbuf);

    dim3 gg(1024 / 128, M_ / 128);  // (8, 32)
    k_gemm<<<gg, 256, 0, stream>>>(hbuf, wT,                biasws,        qb, nullptr, flag, M_, 1024, 1024);
    k_gemm<<<gg, 256, 0, stream>>>(hbuf, wT + (1ull << 20), biasws + 1024, kb2, nullptr, flag, M_, 1024, 1024);
    k_gemm<<<gg, 256, 0, stream>>>(hbuf, wT + (2ull << 20), biasws + 2048, vb, nullptr, flag, M_, 1024, 1024);

    k_rope<<<16384, 256, 0, stream>>>(qb, kb2, positions);
    k_attn<<<B_ * NH_ * (S_ / 64), 256, 0, stream>>>(qb, kb2, vb, lengths, ao);

    k_gemm<<<gg, 256, 0, stream>>>(ao, wT + (3ull << 20), biasws + 3072,
                                   (unsigned short*)d_out, (float*)d_out, flag, M_, 1024, 1024);
}

// Round 2
// 323.060 us; speedup vs baseline: 1.4205x; 1.4205x over previous
//
#include <hip/hip_runtime.h>
#include <hip/hip_bf16.h>
#include <cstdint>

#define DEVINL __device__ __forceinline__

typedef __attribute__((ext_vector_type(8))) short short8;   // 8 x bf16
typedef __attribute__((ext_vector_type(4))) short bhalf4;   // 4 x bf16
typedef __attribute__((ext_vector_type(4))) float f32x4;

constexpr int B_ = 2, S_ = 2048, H_ = 1024, NH_ = 16, HD_ = 64;
constexpr int M_ = B_ * S_;          // 4096 token rows
constexpr float SCALE = 0.125f;      // 1/sqrt(64)

DEVINL float bf2f(unsigned short h) {
    unsigned u = ((unsigned)h) << 16;
    float f; __builtin_memcpy(&f, &u, 4); return f;
}
DEVINL unsigned short f2bf(float f) {  // RNE
    unsigned u; __builtin_memcpy(&u, &f, 4);
    u += 0x7FFFu + ((u >> 16) & 1u);
    return (unsigned short)(u >> 16);
}
DEVINL float ldin(const void* p, size_t i, int fp32) {
    return fp32 ? ((const float*)p)[i] : bf2f(((const unsigned short*)p)[i]);
}
DEVINL void gl16(const void* g, void* l) {  // async global->LDS, 16B/lane
    __builtin_amdgcn_global_load_lds(
        (const __attribute__((address_space(1))) unsigned int*)g,
        (__attribute__((address_space(3))) unsigned int*)l, 16, 0, 0);
}
DEVINL f32x4 mfma16(short8 a, short8 b, f32x4 c) {
    return __builtin_amdgcn_mfma_f32_16x16x32_bf16(a, b, c, 0, 0, 0);
}
DEVINL f32x4 mfma16x16(bhalf4 a, bhalf4 b, f32x4 c) {
#if __has_builtin(__builtin_amdgcn_mfma_f32_16x16x16bf16_1k)
    return __builtin_amdgcn_mfma_f32_16x16x16bf16_1k(a, b, c, 0, 0, 0);
#else
    f32x4 d;
    asm volatile("v_mfma_f32_16x16x16_bf16 %0, %1, %2, %3\n\t"
                 "s_nop 7\n\ts_nop 7"
                 : "=v"(d) : "v"(a), "v"(b), "v"(c));
    return d;
#endif
}
DEVINL void fsincos(float rev01, float* sn, float* cs) {  // input: revolutions in [0,1)
#if __has_builtin(__builtin_amdgcn_sinf) && __has_builtin(__builtin_amdgcn_cosf)
    *sn = __builtin_amdgcn_sinf(rev01);
    *cs = __builtin_amdgcn_cosf(rev01);
#else
    float a = rev01 * 6.28318530717958647692f;
    *sn = __sinf(a); *cs = __cosf(a);
#endif
}

// ---------------------------------------------------------------------------
// Mode detect: fp32 vs bf16 inputs (see R1 notes). flag=1 -> fp32.
// ---------------------------------------------------------------------------
__global__ __launch_bounds__(256) void k_detect(const unsigned short* __restrict__ emb,
                                                int* __restrict__ flag) {
    int t = threadIdx.x;
    unsigned short hw = emb[2 * t];
    unsigned e = (hw >> 7) & 0xFFu;
    int plaus = ((e >= 90u) && (e <= 126u)) || ((hw & 0x7FFFu) == 0u);
    __shared__ int cnt[4];
    int s = plaus;
    #pragma unroll
    for (int o = 1; o < 64; o <<= 1) s += __shfl_xor(s, o);
    if ((t & 63) == 0) cnt[t >> 6] = s;
    __syncthreads();
    if (t == 0) flag[0] = ((cnt[0] + cnt[1] + cnt[2] + cnt[3]) > 192) ? 0 : 1;
}

__global__ __launch_bounds__(256) void k_bias(const void* bq, const void* bk,
                                              const void* bv, const void* bo,
                                              const int* __restrict__ flag,
                                              float* __restrict__ out) {
    int i = blockIdx.x * 256 + threadIdx.x;  // 0..4095
    int fp32 = flag[0];
    const void* src = (i < 1024) ? bq : (i < 2048) ? bk : (i < 3072) ? bv : bo;
    out[i] = ldin(src, (size_t)(i & 1023), fp32);
}

// Transpose+convert 1024x1024 weight -> wT[n][k] (bf16).
__global__ __launch_bounds__(256) void k_transw(const void* w0, const void* w1,
                                                const void* w2, const void* w3,
                                                const int* __restrict__ flag,
                                                unsigned short* __restrict__ wT) {
    __shared__ float tile[32][33];
    int mat = blockIdx.z;
    const void* w = (mat == 0) ? w0 : (mat == 1) ? w1 : (mat == 2) ? w2 : w3;
    int fp32 = flag[0];
    int n0 = blockIdx.x * 32, k0 = blockIdx.y * 32;
    int tx = threadIdx.x, ty = threadIdx.y;
    for (int i = ty; i < 32; i += 8)
        tile[i][tx] = ldin(w, (size_t)(k0 + i) * 1024 + n0 + tx, fp32);
    __syncthreads();
    unsigned short* dst = wT + (size_t)mat * 1024 * 1024;
    for (int i = ty; i < 32; i += 8)
        dst[(size_t)(n0 + i) * 1024 + k0 + tx] = f2bf(tile[tx][i]);
}

// Embedding gather -> bf16 h (4096 x 1024).
__global__ __launch_bounds__(256) void k_gather(const int* __restrict__ batch,
                                                const void* __restrict__ emb,
                                                const int* __restrict__ flag,
                                                unsigned short* __restrict__ h) {
    int row = blockIdx.x, t = threadIdx.x;
    int tok = batch[row];
    unsigned short* dst = h + (size_t)row * H_;
    if (flag[0]) {
        const float4* s = (const float4*)((const float*)emb + (size_t)tok * H_);
        float4 x = s[t];
        unsigned long long pk = (unsigned long long)f2bf(x.x)
                              | ((unsigned long long)f2bf(x.y) << 16)
                              | ((unsigned long long)f2bf(x.z) << 32)
                              | ((unsigned long long)f2bf(x.w) << 48);
        ((unsigned long long*)dst)[t] = pk;
    } else {
        ((uint2*)dst)[t] =
            ((const uint2*)((const unsigned short*)emb + (size_t)tok * H_))[t];
    }
}

// ---------------------------------------------------------------------------
// Fused QKV GEMM (M=4096, N=3072, K=1024), 128x128 tiles, RoPE fused into the
// epilogue for the q/k thirds. Bt rows 0..1023 = wq^T, 1024.. = wk^T, 2048.. = wv^T.
// ---------------------------------------------------------------------------
__global__ __launch_bounds__(256) void k_gemm_qkv(const unsigned short* __restrict__ A,
                                                  const unsigned short* __restrict__ Bt,
                                                  const float* __restrict__ bias,
                                                  const int* __restrict__ positions,
                                                  unsigned short* __restrict__ qo,
                                                  unsigned short* __restrict__ ko,
                                                  unsigned short* __restrict__ vo) {
    constexpr int K = 1024;
    __shared__ alignas(16) unsigned short As[128 * 32];
    __shared__ alignas(16) unsigned short Bs[128 * 32];
    int t = threadIdx.x, lane = t & 63, quad = lane >> 4, n16 = lane & 15;
    int w = t >> 6, wm = w >> 1, wn = w & 1;
    int m0 = blockIdx.y * 128, n0 = blockIdx.x * 128;
    f32x4 acc[4][4];
    #pragma unroll
    for (int mi = 0; mi < 4; mi++)
        #pragma unroll
        for (int ni = 0; ni < 4; ni++) acc[mi][ni] = (f32x4){0.f, 0.f, 0.f, 0.f};
    int c0 = t, c1 = t + 256;
    int ra0 = c0 >> 2, ka0 = (c0 & 3) * 8;
    int ra1 = c1 >> 2, ka1 = (c1 & 3) * 8;
    for (int k0 = 0; k0 < K; k0 += 32) {
        __syncthreads();
        gl16(A  + (size_t)(m0 + ra0) * K + k0 + ka0, &As[c0 * 8]);
        gl16(A  + (size_t)(m0 + ra1) * K + k0 + ka1, &As[c1 * 8]);
        gl16(Bt + (size_t)(n0 + ra0) * K + k0 + ka0, &Bs[c0 * 8]);
        gl16(Bt + (size_t)(n0 + ra1) * K + k0 + ka1, &Bs[c1 * 8]);
        __syncthreads();
        short8 af[4], bfr[4];
        #pragma unroll
        for (int mi = 0; mi < 4; mi++)
            af[mi] = *(const short8*)&As[(wm * 64 + mi * 16 + n16) * 32 + quad * 8];
        #pragma unroll
        for (int ni = 0; ni < 4; ni++)
            bfr[ni] = *(const short8*)&Bs[(wn * 64 + ni * 16 + n16) * 32 + quad * 8];
        #pragma unroll
        for (int mi = 0; mi < 4; mi++)
            #pragma unroll
            for (int ni = 0; ni < 4; ni++)
                acc[mi][ni] = mfma16(af[mi], bfr[ni], acc[mi][ni]);
    }
    int colbase = n0 + wn * 64;               // multiple of 64: one buf, one head
    int buf = colbase >> 10;                  // 0=q 1=k 2=v (uniform per block half)
    unsigned short* out = (buf == 0) ? qo : (buf == 1) ? ko : vo;
    int cc = colbase & 1023;
    float bb[4];
    #pragma unroll
    for (int ni = 0; ni < 4; ni++) bb[ni] = bias[colbase + ni * 16 + n16];
    if (buf == 2) {
        #pragma unroll
        for (int mi = 0; mi < 4; mi++)
            #pragma unroll
            for (int ni = 0; ni < 4; ni++) {
                int row = m0 + wm * 64 + mi * 16 + quad * 4;
                #pragma unroll
                for (int i = 0; i < 4; i++)
                    out[(size_t)(row + i) * 1024 + cc + ni * 16 + n16] =
                        f2bf(acc[mi][ni][i] + bb[ni]);
            }
    } else {
        // RoPE: d = ni*16+n16 (<32 for ni<2); pair is (ni, ni+2).
        float revf[2];
        #pragma unroll
        for (int ni = 0; ni < 2; ni++) {
            float d = (float)(ni * 16 + n16);
            revf[ni] = __expf(d * -0.28782313f) * 0.15915494f;  // invf / 2pi
        }
        #pragma unroll
        for (int mi = 0; mi < 4; mi++) {
            int row0 = m0 + wm * 64 + mi * 16 + quad * 4;
            #pragma unroll
            for (int i = 0; i < 4; i++) {
                int row = row0 + i;
                float pos = (float)positions[row];
                #pragma unroll
                for (int ni = 0; ni < 2; ni++) {
                    float rev = pos * revf[ni];
                    float fr = rev - floorf(rev);
                    float sn, cs; fsincos(fr, &sn, &cs);
                    float x1 = acc[mi][ni][i] + bb[ni];
                    float x2 = acc[mi][ni + 2][i] + bb[ni + 2];
                    out[(size_t)row * 1024 + cc + ni * 16 + n16] = f2bf(x1 * cs - x2 * sn);
                    out[(size_t)row * 1024 + cc + (ni + 2) * 16 + n16] = f2bf(x2 * cs + x1 * sn);
                }
            }
        }
    }
}

// ---------------------------------------------------------------------------
// Flash attention v2 (transposed scores). Block = (b, h, j): query tiles
// {j, 31-j} (balanced), 4 waves x 16 queries per set. 64-key tiles.
// S^T = K.Q^T via 16x16x32; P stays in registers (C-layout == A-layout of P);
// PV via 16x16x16 with V^T staged in LDS (stride 68, xor swizzle).
// ---------------------------------------------------------------------------
__global__ __launch_bounds__(256) void k_attn(const unsigned short* __restrict__ q,
                                              const unsigned short* __restrict__ k_,
                                              const unsigned short* __restrict__ v,
                                              const int* __restrict__ lengths,
                                              unsigned short* __restrict__ o) {
    __shared__ alignas(16) unsigned short Ks[64 * 64];   // swizzled 16B chunks
    __shared__ alignas(16) unsigned short Vt[64 * 68];   // [feat][keyslot] stride 68
    int bx = blockIdx.x;
    int j = bx & 15, hh = (bx >> 4) & 15, b = bx >> 8;
    int t = threadIdx.x, w = t >> 6, lane = t & 63, quad = lane >> 4, n16 = lane & 15;
    int len = lengths[b];
    int tile0 = j, tile1 = 31 - j;               // tile1 > tile0
    int kend0 = min(tile0 * 64 + 64, len);
    int kend1 = min(tile1 * 64 + 64, len);
    int nkt = (kend1 + 63) >> 6;
    int qrow0 = tile0 * 64 + w * 16 + n16;
    int qrow1 = tile1 * 64 + w * 16 + n16;
    int limit0 = min(qrow0, len - 1);
    int limit1 = min(qrow1, len - 1);
    short8 qf[2][2];
    {
        size_t qa = ((size_t)(b * S_ + qrow0)) * H_ + hh * 64 + quad * 8;
        size_t qb2 = ((size_t)(b * S_ + qrow1)) * H_ + hh * 64 + quad * 8;
        qf[0][0] = *(const short8*)(q + qa);  qf[0][1] = *(const short8*)(q + qa + 32);
        qf[1][0] = *(const short8*)(q + qb2); qf[1][1] = *(const short8*)(q + qb2 + 32);
    }
    f32x4 oa[2][4];
    float m_[2], l_[2];
    #pragma unroll
    for (int s = 0; s < 2; s++) {
        m_[s] = -__builtin_inff(); l_[s] = 0.f;
        #pragma unroll
        for (int nb = 0; nb < 4; nb++) oa[s][nb] = (f32x4){0.f, 0.f, 0.f, 0.f};
    }
    int vkey = t >> 3, vc = t & 7;               // V staging: key (+32), feat chunk
    for (int kt = 0; kt < nkt; kt++) {
        int kb = kt * 64;
        __syncthreads();
        {   // K staging: swizzled source chunks, contiguous LDS (gl16 dest rule)
            int s0 = t;        int ky = s0 >> 3; int ch = (s0 & 7) ^ (ky & 7);
            gl16(k_ + ((size_t)(b * S_ + kb + ky)) * H_ + hh * 64 + ch * 8, &Ks[s0 * 8]);
            int s1 = t + 256;  ky = s1 >> 3;     ch = (s1 & 7) ^ (ky & 7);
            gl16(k_ + ((size_t)(b * S_ + kb + ky)) * H_ + hh * 64 + ch * 8, &Ks[s1 * 8]);
        }
        #pragma unroll
        for (int hlf = 0; hlf < 2; hlf++) {      // V staging: transpose into Vt
            int ky = vkey + hlf * 32;
            short8 vv = *(const short8*)(v + ((size_t)(b * S_ + kb + ky)) * H_ + hh * 64 + vc * 8);
            int slot = ky ^ ((vc >> 1) << 2);
            #pragma unroll
            for (int jj = 0; jj < 8; jj++)
                Vt[(vc * 8 + jj) * 68 + slot] = (unsigned short)vv[jj];
        }
        __syncthreads();
        short8 kf[4][2];                         // K A-frags, shared by both sets
        #pragma unroll
        for (int st = 0; st < 4; st++)
            #pragma unroll
            for (int hf = 0; hf < 2; hf++) {
                int ky = st * 16 + n16;
                int slot = ky * 8 + ((hf * 4 + quad) ^ (ky & 7));
                kf[st][hf] = *(const short8*)&Ks[slot * 8];
            }
        bhalf4 vf[4][4];                         // V^T B-frags, shared
        #pragma unroll
        for (int st = 0; st < 4; st++)
            #pragma unroll
            for (int nb = 0; nb < 4; nb++) {
                int slot = (st * 16 + quad * 4) ^ (nb << 2);
                vf[st][nb] = *(const bhalf4*)&Vt[(nb * 16 + n16) * 68 + slot];
            }
        #pragma unroll
        for (int si = 0; si < 2; si++) {
            if (si == 0 && kb >= kend0) continue;  // set0 done (uniform branch)
            int limit = si ? limit1 : limit0;
            f32x4 sc[4];
            #pragma unroll
            for (int st = 0; st < 4; st++) {
                f32x4 z = (f32x4){0.f, 0.f, 0.f, 0.f};
                z = mfma16(kf[st][0], qf[si][0], z);
                z = mfma16(kf[st][1], qf[si][1], z);
                sc[st] = z;
            }
            float mx = -__builtin_inff();
            #pragma unroll
            for (int st = 0; st < 4; st++)
                #pragma unroll
                for (int i = 0; i < 4; i++) {
                    int kg = kb + st * 16 + quad * 4 + i;
                    float val = sc[st][i] * SCALE;
                    val = (kg <= limit) ? val : -__builtin_inff();
                    sc[st][i] = val;
                    mx = fmaxf(mx, val);
                }
            mx = fmaxf(mx, __shfl_xor(mx, 16));
            mx = fmaxf(mx, __shfl_xor(mx, 32));
            float mnew = fmaxf(m_[si], mx);
            float alpha = __expf(m_[si] - mnew);
            m_[si] = mnew;
            float rs = 0.f;
            bhalf4 pf[4];
            #pragma unroll
            for (int st = 0; st < 4; st++)
                #pragma unroll
                for (int i = 0; i < 4; i++) {
                    float p = __expf(sc[st][i] - mnew);
                    rs += p;
                    pf[st][i] = (short)f2bf(p);
                }
            rs += __shfl_xor(rs, 16);
            rs += __shfl_xor(rs, 32);
            l_[si] = alpha * l_[si] + rs;
            f32x4 av;
            #pragma unroll
            for (int i = 0; i < 4; i++) av[i] = __shfl(alpha, quad * 4 + i);
            #pragma unroll
            for (int nb = 0; nb < 4; nb++) oa[si][nb] *= av;
            #pragma unroll
            for (int st = 0; st < 4; st++)
                #pragma unroll
                for (int nb = 0; nb < 4; nb++)
                    oa[si][nb] = mfma16x16(pf[st], vf[st][nb], oa[si][nb]);
        }
    }
    #pragma unroll
    for (int si = 0; si < 2; si++) {
        int tb = si ? tile1 : tile0;
        f32x4 rl;
        #pragma unroll
        for (int i = 0; i < 4; i++) rl[i] = 1.f / __shfl(l_[si], quad * 4 + i);
        #pragma unroll
        for (int nb = 0; nb < 4; nb++) {
            #pragma unroll
            for (int i = 0; i < 4; i++) {
                int row = tb * 64 + w * 16 + quad * 4 + i;
                o[((size_t)(b * S_ + row)) * H_ + hh * 64 + nb * 16 + n16] =
                    f2bf(oa[si][nb][i] * rl[i]);
            }
        }
    }
}

// ---------------------------------------------------------------------------
// Final projection GEMM, 64x128 tiles (grid 512 = 2 blocks/CU).
// ---------------------------------------------------------------------------
__global__ __launch_bounds__(256) void k_gemm64(const unsigned short* __restrict__ A,
                                                const unsigned short* __restrict__ Bt,
                                                const float* __restrict__ bias,
                                                unsigned short* __restrict__ Cb,
                                                float* __restrict__ Cf,
                                                const int* __restrict__ flag) {
    constexpr int K = 1024, N = 1024;
    __shared__ alignas(16) unsigned short As[64 * 32];
    __shared__ alignas(16) unsigned short Bs[128 * 32];
    int t = threadIdx.x, lane = t & 63, quad = lane >> 4, n16 = lane & 15;
    int w = t >> 6, wm = w & 1, wn = w >> 1;
    int m0 = blockIdx.y * 64, n0 = blockIdx.x * 128;
    f32x4 acc[2][4];
    #pragma unroll
    for (int mi = 0; mi < 2; mi++)
        #pragma unroll
        for (int ni = 0; ni < 4; ni++) acc[mi][ni] = (f32x4){0.f, 0.f, 0.f, 0.f};
    int ra = t >> 2, ka = (t & 3) * 8;
    int rb1 = (t + 256) >> 2, kb1 = ((t + 256) & 3) * 8;
    for (int k0 = 0; k0 < K; k0 += 32) {
        __syncthreads();
        gl16(A  + (size_t)(m0 + ra) * K + k0 + ka, &As[t * 8]);
        gl16(Bt + (size_t)(n0 + ra) * K + k0 + ka, &Bs[t * 8]);
        gl16(Bt + (size_t)(n0 + rb1) * K + k0 + kb1, &Bs[(t + 256) * 8]);
        __syncthreads();
        short8 af[2], bfr[4];
        #pragma unroll
        for (int mi = 0; mi < 2; mi++)
            af[mi] = *(const short8*)&As[(wm * 32 + mi * 16 + n16) * 32 + quad * 8];
        #pragma unroll
        for (int ni = 0; ni < 4; ni++)
            bfr[ni] = *(const short8*)&Bs[(wn * 64 + ni * 16 + n16) * 32 + quad * 8];
        #pragma unroll
        for (int mi = 0; mi < 2; mi++)
            #pragma unroll
            for (int ni = 0; ni < 4; ni++)
                acc[mi][ni] = mfma16(af[mi], bfr[ni], acc[mi][ni]);
    }
    int fp32out = (flag[0] == 1);
    #pragma unroll
    for (int mi = 0; mi < 2; mi++) {
        #pragma unroll
        for (int ni = 0; ni < 4; ni++) {
            int row = m0 + wm * 32 + mi * 16 + quad * 4;
            int col = n0 + wn * 64 + ni * 16 + n16;
            float bb = bias[col];
            #pragma unroll
            for (int i = 0; i < 4; i++) {
                float val = acc[mi][ni][i] + bb;
                size_t idx = (size_t)(row + i) * N + col;
                if (fp32out) Cf[idx] = val;
                else         Cb[idx] = f2bf(val);
            }
        }
    }
}

extern "C" void kernel_launch(void* const* d_in, const int* in_sizes, int n_in,
                              void* d_out, int out_size, void* d_ws, size_t ws_size,
                              hipStream_t stream) {
    (void)in_sizes; (void)n_in; (void)out_size; (void)ws_size;
    const int* batch     = (const int*)d_in[0];
    const int* positions = (const int*)d_in[1];
    const int* lengths   = (const int*)d_in[2];
    const void* emb = d_in[3];
    const void* wq = d_in[4];  const void* bq = d_in[5];
    const void* wk = d_in[6];  const void* bk = d_in[7];
    const void* wv = d_in[8];  const void* bv = d_in[9];
    const void* wo = d_in[10]; const void* bo = d_in[11];

    char* ws = (char*)d_ws;
    int*   flag   = (int*)ws;                                   // 4 KB slot
    float* biasws = (float*)(ws + 4096);                        // 16 KB [bq|bk|bv|bo]
    unsigned short* wT = (unsigned short*)(ws + 20480);         // 4 x 1M bf16
    size_t off = 20480 + (8ull << 20);
    unsigned short* hbuf = (unsigned short*)(ws + off); off += (8ull << 20);
    unsigned short* qb   = (unsigned short*)(ws + off); off += (8ull << 20);
    unsigned short* kb2  = (unsigned short*)(ws + off); off += (8ull << 20);
    unsigned short* vb   = (unsigned short*)(ws + off); off += (8ull << 20);
    unsigned short* ao   = (unsigned short*)(ws + off); off += (8ull << 20);

    k_detect<<<1, 256, 0, stream>>>((const unsigned short*)emb, flag);
    k_bias<<<16, 256, 0, stream>>>(bq, bk, bv, bo, flag, biasws);
    k_transw<<<dim3(32, 32, 4), dim3(32, 8), 0, stream>>>(wq, wk, wv, wo, flag, wT);
    k_gather<<<M_, 256, 0, stream>>>(batch, emb, flag, hbuf);

    k_gemm_qkv<<<dim3(3072 / 128, M_ / 128), 256, 0, stream>>>(
        hbuf, wT, biasws, positions, qb, kb2, vb);

    k_attn<<<B_ * NH_ * 16, 256, 0, stream>>>(qb, kb2, vb, lengths, ao);

    k_gemm64<<<dim3(1024 / 128, M_ / 64), 256, 0, stream>>>(
        ao, wT + (3ull << 20), biasws + 3072,
        (unsigned short*)d_out, (float*)d_out, flag);
}

// Round 3
// 320.077 us; speedup vs baseline: 1.4337x; 1.0093x over previous
//
#include <hip/hip_runtime.h>
#include <hip/hip_bf16.h>
#include <cstdint>

#define DEVINL __device__ __forceinline__

typedef __attribute__((ext_vector_type(8))) short short8;   // 8 x bf16
typedef __attribute__((ext_vector_type(4))) short bhalf4;   // 4 x bf16
typedef __attribute__((ext_vector_type(4))) float f32x4;

constexpr int B_ = 2, S_ = 2048, H_ = 1024, NH_ = 16, HD_ = 64;
constexpr int M_ = B_ * S_;          // 4096 token rows
constexpr float SCALE = 0.125f;      // 1/sqrt(64)

DEVINL float bf2f(unsigned short h) {
    unsigned u = ((unsigned)h) << 16;
    float f; __builtin_memcpy(&f, &u, 4); return f;
}
DEVINL unsigned short f2bf(float f) {  // RNE
    unsigned u; __builtin_memcpy(&u, &f, 4);
    u += 0x7FFFu + ((u >> 16) & 1u);
    return (unsigned short)(u >> 16);
}
DEVINL float ldin(const void* p, size_t i, int fp32) {
    return fp32 ? ((const float*)p)[i] : bf2f(((const unsigned short*)p)[i]);
}
DEVINL void gl16(const void* g, void* l) {  // async global->LDS, 16B/lane
    __builtin_amdgcn_global_load_lds(
        (const __attribute__((address_space(1))) unsigned int*)g,
        (__attribute__((address_space(3))) unsigned int*)l, 16, 0, 0);
}
DEVINL f32x4 mfma16(short8 a, short8 b, f32x4 c) {
    return __builtin_amdgcn_mfma_f32_16x16x32_bf16(a, b, c, 0, 0, 0);
}
DEVINL void fsincos(float rev01, float* sn, float* cs) {  // revolutions in [0,1)
#if __has_builtin(__builtin_amdgcn_sinf) && __has_builtin(__builtin_amdgcn_cosf)
    *sn = __builtin_amdgcn_sinf(rev01);
    *cs = __builtin_amdgcn_cosf(rev01);
#else
    float a = rev01 * 6.28318530717958647692f;
    *sn = __sinf(a); *cs = __cosf(a);
#endif
}
// Mode detect helper: bf16 plausibility of even halfwords of emb (see R1 notes).
DEVINL int detect_fp32(const unsigned short* emb, int t) {
    unsigned short hw = emb[2 * t];
    unsigned e = (hw >> 7) & 0xFFu;
    int s = (((e >= 90u) && (e <= 126u)) || ((hw & 0x7FFFu) == 0u)) ? 1 : 0;
    #pragma unroll
    for (int o = 1; o < 64; o <<= 1) s += __shfl_xor(s, o);
    __shared__ int cnt[4];
    if ((t & 63) == 0) cnt[t >> 6] = s;
    __syncthreads();
    return ((cnt[0] + cnt[1] + cnt[2] + cnt[3]) > 192) ? 0 : 1;
}

// ---------------------------------------------------------------------------
// Bias concat + mode detect (block 0 publishes flag for later kernels).
// ---------------------------------------------------------------------------
__global__ __launch_bounds__(256) void k_bias(const void* bq, const void* bk,
                                              const void* bv, const void* bo,
                                              const unsigned short* __restrict__ emb,
                                              int* __restrict__ flag,
                                              float* __restrict__ out) {
    int t = threadIdx.x;
    int fp32 = detect_fp32(emb, t);
    if (blockIdx.x == 0 && t == 0) flag[0] = fp32;
    int i = blockIdx.x * 256 + t;  // 0..4095
    const void* src = (i < 1024) ? bq : (i < 2048) ? bk : (i < 3072) ? bv : bo;
    out[i] = ldin(src, (size_t)(i & 1023), fp32);
}

// Transpose+convert 1024x1024 weight -> wT[n][k] (bf16).
__global__ __launch_bounds__(256) void k_transw(const void* w0, const void* w1,
                                                const void* w2, const void* w3,
                                                const int* __restrict__ flag,
                                                unsigned short* __restrict__ wT) {
    __shared__ float tile[32][33];
    int mat = blockIdx.z;
    const void* w = (mat == 0) ? w0 : (mat == 1) ? w1 : (mat == 2) ? w2 : w3;
    int fp32 = flag[0];
    int n0 = blockIdx.x * 32, k0 = blockIdx.y * 32;
    int tx = threadIdx.x, ty = threadIdx.y;
    for (int i = ty; i < 32; i += 8)
        tile[i][tx] = ldin(w, (size_t)(k0 + i) * 1024 + n0 + tx, fp32);
    __syncthreads();
    unsigned short* dst = wT + (size_t)mat * 1024 * 1024;
    for (int i = ty; i < 32; i += 8)
        dst[(size_t)(n0 + i) * 1024 + k0 + tx] = f2bf(tile[tx][i]);
}

// Embedding gather -> bf16 h. Only needed in fp32 mode (bf16 mode: QKV reads
// emb directly through batch[]); early-out otherwise.
__global__ __launch_bounds__(256) void k_gather(const int* __restrict__ batch,
                                                const void* __restrict__ emb,
                                                const int* __restrict__ flag,
                                                unsigned short* __restrict__ h) {
    if (flag[0] == 0) return;
    int row = blockIdx.x, t = threadIdx.x;
    int tok = batch[row];
    const float4* s = (const float4*)((const float*)emb + (size_t)tok * H_);
    float4 x = s[t];
    unsigned long long pk = (unsigned long long)f2bf(x.x)
                          | ((unsigned long long)f2bf(x.y) << 16)
                          | ((unsigned long long)f2bf(x.z) << 32)
                          | ((unsigned long long)f2bf(x.w) << 48);
    ((unsigned long long*)(h + (size_t)row * H_))[t] = pk;
}

// ---------------------------------------------------------------------------
// Fused QKV GEMM (M=4096, N=3072, K=1024), 128x128 tiles, BK=64 as two BK=32
// panels (half the barrier drains). A staged straight from emb via batch[] in
// bf16 mode. Epilogue: RoPE fused for q/k; V written TRANSPOSED to global
// vt[b][feat(1024)][seq(2048)] for the attention stage.
// ---------------------------------------------------------------------------
__global__ __launch_bounds__(256) void k_gemm_qkv(const unsigned short* __restrict__ embb,
                                                  const unsigned short* __restrict__ hbuf,
                                                  const int* __restrict__ batch,
                                                  const unsigned short* __restrict__ Bt,
                                                  const float* __restrict__ bias,
                                                  const int* __restrict__ positions,
                                                  const int* __restrict__ flag,
                                                  unsigned short* __restrict__ qo,
                                                  unsigned short* __restrict__ ko,
                                                  unsigned short* __restrict__ vt) {
    constexpr int K = 1024;
    __shared__ alignas(16) unsigned short As[2][128 * 32];
    __shared__ alignas(16) unsigned short Bs[2][128 * 32];
    int t = threadIdx.x, lane = t & 63, quad = lane >> 4, n16 = lane & 15;
    int w = t >> 6, wm = w >> 1, wn = w & 1;
    int m0 = blockIdx.y * 128, n0 = blockIdx.x * 128;
    int fp32 = flag[0];
    int r0 = t >> 2, r1 = 64 + r0;        // (t+256)>>2
    int ka = (t & 3) * 8;
    const unsigned short* a0;
    const unsigned short* a1;
    if (fp32) {
        a0 = hbuf + (size_t)(m0 + r0) * K;
        a1 = hbuf + (size_t)(m0 + r1) * K;
    } else {
        a0 = embb + (size_t)batch[m0 + r0] * K;
        a1 = embb + (size_t)batch[m0 + r1] * K;
    }
    const unsigned short* b0 = Bt + (size_t)(n0 + r0) * K;
    const unsigned short* b1 = Bt + (size_t)(n0 + r1) * K;
    f32x4 acc[4][4];
    #pragma unroll
    for (int mi = 0; mi < 4; mi++)
        #pragma unroll
        for (int ni = 0; ni < 4; ni++) acc[mi][ni] = (f32x4){0.f, 0.f, 0.f, 0.f};
    for (int k0 = 0; k0 < K; k0 += 64) {
        __syncthreads();
        gl16(a0 + k0 + ka,      &As[0][t * 8]);
        gl16(a1 + k0 + ka,      &As[0][(t + 256) * 8]);
        gl16(a0 + k0 + 32 + ka, &As[1][t * 8]);
        gl16(a1 + k0 + 32 + ka, &As[1][(t + 256) * 8]);
        gl16(b0 + k0 + ka,      &Bs[0][t * 8]);
        gl16(b1 + k0 + ka,      &Bs[0][(t + 256) * 8]);
        gl16(b0 + k0 + 32 + ka, &Bs[1][t * 8]);
        gl16(b1 + k0 + 32 + ka, &Bs[1][(t + 256) * 8]);
        __syncthreads();
        #pragma unroll
        for (int ks = 0; ks < 2; ks++) {
            short8 af[4], bfr[4];
            #pragma unroll
            for (int mi = 0; mi < 4; mi++)
                af[mi] = *(const short8*)&As[ks][(wm * 64 + mi * 16 + n16) * 32 + quad * 8];
            #pragma unroll
            for (int ni = 0; ni < 4; ni++)
                bfr[ni] = *(const short8*)&Bs[ks][(wn * 64 + ni * 16 + n16) * 32 + quad * 8];
            #pragma unroll
            for (int mi = 0; mi < 4; mi++)
                #pragma unroll
                for (int ni = 0; ni < 4; ni++)
                    acc[mi][ni] = mfma16(af[mi], bfr[ni], acc[mi][ni]);
        }
    }
    int colbase = n0 + wn * 64;               // multiple of 64: one buf, one head
    int buf = colbase >> 10;                  // 0=q 1=k 2=v
    int cc = colbase & 1023;
    float bb[4];
    #pragma unroll
    for (int ni = 0; ni < 4; ni++) bb[ni] = bias[colbase + ni * 16 + n16];
    if (buf == 2) {
        // V^T: vt[b][feat][seq], 8B packed stores (4 consecutive seq per chunk)
        #pragma unroll
        for (int mi = 0; mi < 4; mi++) {
            int row = m0 + wm * 64 + mi * 16 + quad * 4;
            int bb_ = row >> 11, s0 = row & 2047;
            #pragma unroll
            for (int ni = 0; ni < 4; ni++) {
                int f = cc + ni * 16 + n16;
                unsigned long long pk = 0;
                #pragma unroll
                for (int i = 0; i < 4; i++)
                    pk |= (unsigned long long)f2bf(acc[mi][ni][i] + bb[ni]) << (16 * i);
                *(unsigned long long*)(vt + ((size_t)(bb_ * 1024 + f)) * 2048 + s0) = pk;
            }
        }
    } else {
        unsigned short* out = (buf == 0) ? qo : ko;
        float revf[2];
        #pragma unroll
        for (int ni = 0; ni < 2; ni++) {
            float d = (float)(ni * 16 + n16);
            revf[ni] = __expf(d * -0.28782313f) * 0.15915494f;  // invf / 2pi
        }
        #pragma unroll
        for (int mi = 0; mi < 4; mi++) {
            int row0 = m0 + wm * 64 + mi * 16 + quad * 4;
            #pragma unroll
            for (int i = 0; i < 4; i++) {
                int row = row0 + i;
                float pos = (float)positions[row];
                #pragma unroll
                for (int ni = 0; ni < 2; ni++) {
                    float rev = pos * revf[ni];
                    float fr = rev - floorf(rev);
                    float sn, cs; fsincos(fr, &sn, &cs);
                    float x1 = acc[mi][ni][i] + bb[ni];
                    float x2 = acc[mi][ni + 2][i] + bb[ni + 2];
                    out[(size_t)row * 1024 + cc + ni * 16 + n16] = f2bf(x1 * cs - x2 * sn);
                    out[(size_t)row * 1024 + cc + (ni + 2) * 16 + n16] = f2bf(x2 * cs + x1 * sn);
                }
            }
        }
    }
}

// ---------------------------------------------------------------------------
// Flash attention v3. Block = (b,h,j): balanced query tiles {j, 31-j}.
// S^T = K.Q^T (C-layout regs == A-layout of P, no LDS round-trip).
// K staged row-major, V staged from global V^T — both via gl16 with source
// chunk XOR swizzle; PV via paired 16x16x32 MFMA.
// ---------------------------------------------------------------------------
__global__ __launch_bounds__(256) void k_attn(const unsigned short* __restrict__ q,
                                              const unsigned short* __restrict__ k_,
                                              const unsigned short* __restrict__ vt,
                                              const int* __restrict__ lengths,
                                              unsigned short* __restrict__ o) {
    __shared__ alignas(16) unsigned short Ks[64 * 64];   // [key][feat] swizzled
    __shared__ alignas(16) unsigned short Vs[64 * 64];   // [feat][key] swizzled
    int bx = blockIdx.x;
    int j = bx & 15, hh = (bx >> 4) & 15, b = bx >> 8;
    int t = threadIdx.x, w = t >> 6, lane = t & 63, quad = lane >> 4, n16 = lane & 15;
    int len = lengths[b];
    int tile0 = j, tile1 = 31 - j;               // tile1 > tile0
    int kend0 = min(tile0 * 64 + 64, len);
    int kend1 = min(tile1 * 64 + 64, len);
    int nkt = (kend1 + 63) >> 6;
    int qrow0 = tile0 * 64 + w * 16 + n16;
    int qrow1 = tile1 * 64 + w * 16 + n16;
    int limit0 = min(qrow0, len - 1);
    int limit1 = min(qrow1, len - 1);
    short8 qf[2][2];
    {
        size_t qa = ((size_t)(b * S_ + qrow0)) * H_ + hh * 64 + quad * 8;
        size_t qb2 = ((size_t)(b * S_ + qrow1)) * H_ + hh * 64 + quad * 8;
        qf[0][0] = *(const short8*)(q + qa);  qf[0][1] = *(const short8*)(q + qa + 32);
        qf[1][0] = *(const short8*)(q + qb2); qf[1][1] = *(const short8*)(q + qb2 + 32);
    }
    f32x4 oa[2][4];
    float m_[2], l_[2];
    #pragma unroll
    for (int s = 0; s < 2; s++) {
        m_[s] = -__builtin_inff(); l_[s] = 0.f;
        #pragma unroll
        for (int nb = 0; nb < 4; nb++) oa[s][nb] = (f32x4){0.f, 0.f, 0.f, 0.f};
    }
    // staging indices (both rounds share t-derived row/chunk with +256 offset)
    int ky0 = t >> 3,        kc0 = (t & 7) ^ (ky0 & 7);
    int ky1 = (t + 256) >> 3, kc1 = (t & 7) ^ (ky1 & 7);
    const unsigned short* kbase = k_ + (size_t)b * S_ * H_ + hh * 64;
    const unsigned short* vbase = vt + ((size_t)(b * 1024 + hh * 64)) * 2048;
    for (int kt = 0; kt < nkt; kt++) {
        int kb = kt * 64;
        __syncthreads();
        gl16(kbase + (size_t)(kb + ky0) * H_ + kc0 * 8, &Ks[t * 8]);
        gl16(kbase + (size_t)(kb + ky1) * H_ + kc1 * 8, &Ks[(t + 256) * 8]);
        gl16(vbase + (size_t)ky0 * 2048 + kb + kc0 * 8, &Vs[t * 8]);
        gl16(vbase + (size_t)ky1 * 2048 + kb + kc1 * 8, &Vs[(t + 256) * 8]);
        __syncthreads();
        short8 kf[4][2];                         // K A-frags (16 keys x 32 feats)
        #pragma unroll
        for (int st = 0; st < 4; st++)
            #pragma unroll
            for (int hf = 0; hf < 2; hf++) {
                int ky = st * 16 + n16;
                int slot = ky * 8 + ((hf * 4 + quad) ^ (ky & 7));
                kf[st][hf] = *(const short8*)&Ks[slot * 8];
            }
        short8 vf8[2][4];                        // V^T B-frags, paired 32-key
        #pragma unroll
        for (int p = 0; p < 2; p++)
            #pragma unroll
            for (int nb = 0; nb < 4; nb++) {
                int f = nb * 16 + n16;
                int cl0 = 4 * p + (quad >> 1);
                int cl1 = cl0 + 2;
                int off = (quad & 1) * 4;
                bhalf4 lo = *(const bhalf4*)&Vs[f * 64 + ((cl0 ^ (f & 7)) * 8 + off)];
                bhalf4 hi = *(const bhalf4*)&Vs[f * 64 + ((cl1 ^ (f & 7)) * 8 + off)];
                short8 cmb = {lo[0], lo[1], lo[2], lo[3], hi[0], hi[1], hi[2], hi[3]};
                vf8[p][nb] = cmb;
            }
        #pragma unroll
        for (int si = 0; si < 2; si++) {
            if (si == 0 && kb >= kend0) continue;  // set0 done (uniform branch)
            int limit = si ? limit1 : limit0;
            f32x4 sc[4];
            #pragma unroll
            for (int st = 0; st < 4; st++) {
                f32x4 z = (f32x4){0.f, 0.f, 0.f, 0.f};
                z = mfma16(kf[st][0], qf[si][0], z);
                z = mfma16(kf[st][1], qf[si][1], z);
                sc[st] = z;
            }
            float mx = -__builtin_inff();
            #pragma unroll
            for (int st = 0; st < 4; st++)
                #pragma unroll
                for (int i = 0; i < 4; i++) {
                    int kg = kb + st * 16 + quad * 4 + i;
                    float val = sc[st][i] * SCALE;
                    val = (kg <= limit) ? val : -__builtin_inff();
                    sc[st][i] = val;
                    mx = fmaxf(mx, val);
                }
            mx = fmaxf(mx, __shfl_xor(mx, 16));
            mx = fmaxf(mx, __shfl_xor(mx, 32));
            float mnew = fmaxf(m_[si], mx);
            float alpha = __expf(m_[si] - mnew);
            m_[si] = mnew;
            float rs = 0.f;
            bhalf4 pf[4];
            #pragma unroll
            for (int st = 0; st < 4; st++)
                #pragma unroll
                for (int i = 0; i < 4; i++) {
                    float p = __expf(sc[st][i] - mnew);
                    rs += p;
                    pf[st][i] = (short)f2bf(p);
                }
            rs += __shfl_xor(rs, 16);
            rs += __shfl_xor(rs, 32);
            l_[si] = alpha * l_[si] + rs;
            f32x4 av;
            #pragma unroll
            for (int i = 0; i < 4; i++) av[i] = __shfl(alpha, quad * 4 + i);
            #pragma unroll
            for (int nb = 0; nb < 4; nb++) oa[si][nb] *= av;
            #pragma unroll
            for (int p = 0; p < 2; p++) {
                short8 pp = {pf[2 * p][0], pf[2 * p][1], pf[2 * p][2], pf[2 * p][3],
                             pf[2 * p + 1][0], pf[2 * p + 1][1], pf[2 * p + 1][2], pf[2 * p + 1][3]};
                #pragma unroll
                for (int nb = 0; nb < 4; nb++)
                    oa[si][nb] = mfma16(pp, vf8[p][nb], oa[si][nb]);
            }
        }
    }
    #pragma unroll
    for (int si = 0; si < 2; si++) {
        int tb = si ? tile1 : tile0;
        f32x4 rl;
        #pragma unroll
        for (int i = 0; i < 4; i++) rl[i] = 1.f / __shfl(l_[si], quad * 4 + i);
        #pragma unroll
        for (int nb = 0; nb < 4; nb++) {
            #pragma unroll
            for (int i = 0; i < 4; i++) {
                int row = tb * 64 + w * 16 + quad * 4 + i;
                o[((size_t)(b * S_ + row)) * H_ + hh * 64 + nb * 16 + n16] =
                    f2bf(oa[si][nb][i] * rl[i]);
            }
        }
    }
}

// ---------------------------------------------------------------------------
// Final projection GEMM, 64x128 tiles, BK=64 two-panel staging.
// ---------------------------------------------------------------------------
__global__ __launch_bounds__(256) void k_gemm64(const unsigned short* __restrict__ A,
                                                const unsigned short* __restrict__ Bt,
                                                const float* __restrict__ bias,
                                                unsigned short* __restrict__ Cb,
                                                float* __restrict__ Cf,
                                                const int* __restrict__ flag) {
    constexpr int K = 1024, N = 1024;
    __shared__ alignas(16) unsigned short As[2][64 * 32];
    __shared__ alignas(16) unsigned short Bs[2][128 * 32];
    int t = threadIdx.x, lane = t & 63, quad = lane >> 4, n16 = lane & 15;
    int w = t >> 6, wm = w & 1, wn = w >> 1;
    int m0 = blockIdx.y * 64, n0 = blockIdx.x * 128;
    int r0 = t >> 2, r1 = 64 + r0, ka = (t & 3) * 8;
    const unsigned short* a0 = A + (size_t)(m0 + r0) * K;
    const unsigned short* b0 = Bt + (size_t)(n0 + r0) * K;
    const unsigned short* b1 = Bt + (size_t)(n0 + r1) * K;
    f32x4 acc[2][4];
    #pragma unroll
    for (int mi = 0; mi < 2; mi++)
        #pragma unroll
        for (int ni = 0; ni < 4; ni++) acc[mi][ni] = (f32x4){0.f, 0.f, 0.f, 0.f};
    for (int k0 = 0; k0 < K; k0 += 64) {
        __syncthreads();
        gl16(a0 + k0 + ka,      &As[0][t * 8]);
        gl16(a0 + k0 + 32 + ka, &As[1][t * 8]);
        gl16(b0 + k0 + ka,      &Bs[0][t * 8]);
        gl16(b1 + k0 + ka,      &Bs[0][(t + 256) * 8]);
        gl16(b0 + k0 + 32 + ka, &Bs[1][t * 8]);
        gl16(b1 + k0 + 32 + ka, &Bs[1][(t + 256) * 8]);
        __syncthreads();
        #pragma unroll
        for (int ks = 0; ks < 2; ks++) {
            short8 af[2], bfr[4];
            #pragma unroll
            for (int mi = 0; mi < 2; mi++)
                af[mi] = *(const short8*)&As[ks][(wm * 32 + mi * 16 + n16) * 32 + quad * 8];
            #pragma unroll
            for (int ni = 0; ni < 4; ni++)
                bfr[ni] = *(const short8*)&Bs[ks][(wn * 64 + ni * 16 + n16) * 32 + quad * 8];
            #pragma unroll
            for (int mi = 0; mi < 2; mi++)
                #pragma unroll
                for (int ni = 0; ni < 4; ni++)
                    acc[mi][ni] = mfma16(af[mi], bfr[ni], acc[mi][ni]);
        }
    }
    int fp32out = (flag[0] == 1);
    #pragma unroll
    for (int mi = 0; mi < 2; mi++) {
        #pragma unroll
        for (int ni = 0; ni < 4; ni++) {
            int row = m0 + wm * 32 + mi * 16 + quad * 4;
            int col = n0 + wn * 64 + ni * 16 + n16;
            float bb = bias[col];
            #pragma unroll
            for (int i = 0; i < 4; i++) {
                float val = acc[mi][ni][i] + bb;
                size_t idx = (size_t)(row + i) * N + col;
                if (fp32out) Cf[idx] = val;
                else         Cb[idx] = f2bf(val);
            }
        }
    }
}

extern "C" void kernel_launch(void* const* d_in, const int* in_sizes, int n_in,
                              void* d_out, int out_size, void* d_ws, size_t ws_size,
                              hipStream_t stream) {
    (void)in_sizes; (void)n_in; (void)out_size; (void)ws_size;
    const int* batch     = (const int*)d_in[0];
    const int* positions = (const int*)d_in[1];
    const int* lengths   = (const int*)d_in[2];
    const void* emb = d_in[3];
    const void* wq = d_in[4];  const void* bq = d_in[5];
    const void* wk = d_in[6];  const void* bk = d_in[7];
    const void* wv = d_in[8];  const void* bv = d_in[9];
    const void* wo = d_in[10]; const void* bo = d_in[11];

    char* ws = (char*)d_ws;
    int*   flag   = (int*)ws;                                   // 4 KB slot
    float* biasws = (float*)(ws + 4096);                        // 16 KB [bq|bk|bv|bo]
    unsigned short* wT = (unsigned short*)(ws + 20480);         // 4 x 1M bf16
    size_t off = 20480 + (8ull << 20);
    unsigned short* hbuf = (unsigned short*)(ws + off); off += (8ull << 20);
    unsigned short* qb   = (unsigned short*)(ws + off); off += (8ull << 20);
    unsigned short* kb2  = (unsigned short*)(ws + off); off += (8ull << 20);
    unsigned short* vtb  = (unsigned short*)(ws + off); off += (8ull << 20);
    unsigned short* ao   = (unsigned short*)(ws + off); off += (8ull << 20);

    k_bias<<<16, 256, 0, stream>>>(bq, bk, bv, bo, (const unsigned short*)emb,
                                   flag, biasws);
    k_transw<<<dim3(32, 32, 4), dim3(32, 8), 0, stream>>>(wq, wk, wv, wo, flag, wT);
    k_gather<<<M_, 256, 0, stream>>>(batch, emb, flag, hbuf);

    k_gemm_qkv<<<dim3(3072 / 128, M_ / 128), 256, 0, stream>>>(
        (const unsigned short*)emb, hbuf, batch, wT, biasws, positions, flag,
        qb, kb2, vtb);

    k_attn<<<B_ * NH_ * 16, 256, 0, stream>>>(qb, kb2, vtb, lengths, ao);

    k_gemm64<<<dim3(1024 / 128, M_ / 64), 256, 0, stream>>>(
        ao, wT + (3ull << 20), biasws + 3072,
        (unsigned short*)d_out, (float*)d_out, flag);
}